// Round 2
// baseline (1131.919 us; speedup 1.0000x reference)
//
#include <hip/hip_runtime.h>
#include <hip/hip_fp16.h>

#define D 64
#define BSH2 8                   // 256 nodes per coarse bucket
#define NPB 256                  // nodes per bucket
#define NB2_MAX 512              // max buckets (N <= 131072)
#define PCHUNK 4096              // edges per partition block
#define CAPP 4608                // packed region capacity per bucket (incl. pad, x4)

// ---------------- utility ----------------

__global__ void zero_f32(float* __restrict__ p, long n) {
    long i = (long)blockIdx.x * blockDim.x + threadIdx.x;
    long stride = (long)gridDim.x * blockDim.x;
    for (; i < n; i += stride) p[i] = 0.0f;
}

__global__ void init_cursors(int* __restrict__ gcur, int NB2) {
    int i = blockIdx.x * blockDim.x + threadIdx.x;
    if (i < NB2) gcur[i] = i * CAPP;
}

// feat16[node*D+j] = half(norm[node] * feat[node*D+j]); one thread per float4
__global__ __launch_bounds__(256) void feat_to_half(const float4* __restrict__ in,
                                                    const float* __restrict__ norm,
                                                    uint2* __restrict__ out, long n4) {
    long i = (long)blockIdx.x * blockDim.x + threadIdx.x;
    if (i < n4) {
        float4 v = in[i];
        float r = norm[i >> 4];
        __half2 a = __floats2half2_rn(v.x * r, v.y * r);
        __half2 b = __floats2half2_rn(v.z * r, v.w * r);
        uint2 u;
        u.x = *(unsigned int*)&a;
        u.y = *(unsigned int*)&b;
        out[i] = u;
    }
}

// ---------------- build: single-pass partition (1024 threads) ----------------
// Output: per-bucket regions of "packed" entries: src | (local_dst << 20), -1 = pad.
// Pad granularity 4 (16 B lines) to keep region inflation ~15%.
__global__ __launch_bounds__(1024) void partition_direct(const int* __restrict__ src,
                                                         const int* __restrict__ dst,
                                                         int* __restrict__ gcur,
                                                         int* __restrict__ packed,
                                                         int E, int NB2) {
    __shared__ int staged[PCHUNK];     // 16 KB sorted chunk
    __shared__ int lhist[NB2_MAX];
    __shared__ int lbase[NB2_MAX];
    __shared__ int lcur[NB2_MAX];
    __shared__ int gbase[NB2_MAX];
    int tid = threadIdx.x;
    int c0 = blockIdx.x * PCHUNK;
    int c1 = c0 + PCHUNK; if (c1 > E) c1 = E;

    if (tid < NB2_MAX) lhist[tid] = 0;
    __syncthreads();

    // 1: histogram
    for (int e = c0 + tid * 4; e + 4 <= c1; e += 4096) {
        int4 d4 = *(const int4*)(dst + e);
        atomicAdd(&lhist[d4.x >> BSH2], 1);
        atomicAdd(&lhist[d4.y >> BSH2], 1);
        atomicAdd(&lhist[d4.z >> BSH2], 1);
        atomicAdd(&lhist[d4.w >> BSH2], 1);
    }
    int tail = c0 + ((c1 - c0) & ~3);
    for (int e = tail + tid; e < c1; e += 1024)
        atomicAdd(&lhist[dst[e] >> BSH2], 1);
    __syncthreads();

    // 2: single-wave exclusive scan over 512 counters (2 barriers total)
    if (tid < 64) {
        const int CPL = NB2_MAX / 64;     // 8 counters per lane
        int tmp[CPL];
        int s = 0;
        int base = tid * CPL;
        #pragma unroll
        for (int j = 0; j < CPL; j++) { tmp[j] = s; s += lhist[base + j]; }
        int incl = s;
        #pragma unroll
        for (int o = 1; o < 64; o <<= 1) {
            int t = __shfl_up(incl, o, 64);
            if (tid >= o) incl += t;
        }
        int excl = incl - s;
        #pragma unroll
        for (int j = 0; j < CPL; j++) {
            lbase[base + j] = excl + tmp[j];
            lcur[base + j]  = excl + tmp[j];
        }
    }
    __syncthreads();

    // 3: place chunk into LDS sorted by bucket
    for (int e = c0 + tid * 4; e + 4 <= c1; e += 4096) {
        int4 d4 = *(const int4*)(dst + e);
        int4 s4 = *(const int4*)(src + e);
        int k, pos;
        k = d4.x >> BSH2; pos = atomicAdd(&lcur[k], 1);
        staged[pos] = s4.x | ((d4.x & (NPB - 1)) << 20);
        k = d4.y >> BSH2; pos = atomicAdd(&lcur[k], 1);
        staged[pos] = s4.y | ((d4.y & (NPB - 1)) << 20);
        k = d4.z >> BSH2; pos = atomicAdd(&lcur[k], 1);
        staged[pos] = s4.z | ((d4.z & (NPB - 1)) << 20);
        k = d4.w >> BSH2; pos = atomicAdd(&lcur[k], 1);
        staged[pos] = s4.w | ((d4.w & (NPB - 1)) << 20);
    }
    for (int e = tail + tid; e < c1; e += 1024) {
        int d = dst[e];
        int k = d >> BSH2;
        int pos = atomicAdd(&lcur[k], 1);
        staged[pos] = src[e] | ((d & (NPB - 1)) << 20);
    }
    __syncthreads();

    // 4: parallel reservations (pad to 4 = one 16 B line)
    if (tid < NB2_MAX && tid < NB2) {
        int c = lhist[tid];
        gbase[tid] = c ? atomicAdd(&gcur[tid], (c + 3) & ~3) : 0;
    }
    __syncthreads();

    // 5: flush — 64 groups of 16 lanes stream lines
    int grp = tid >> 4, sub = tid & 15;
    for (int k = grp; k < NB2; k += 64) {
        int c = lhist[k];
        if (!c) continue;
        int c4 = (c + 3) & ~3;
        int g = gbase[k], base = lbase[k];
        for (int i = sub; i < c4; i += 16)
            packed[g + i] = (i < c) ? staged[base + i] : -1;
    }
}

// ---------------- build: per-node degrees -> norms (count-only) ----------------
__global__ __launch_bounds__(1024) void bucket_norm(const int* __restrict__ packed,
                                                    const int* __restrict__ gcur,
                                                    float* __restrict__ norm,
                                                    float* __restrict__ norm2,
                                                    int N) {
    __shared__ int cnt[NPB];
    int b = blockIdx.x;
    int tid = threadIdx.x;
    if (tid < NPB) cnt[tid] = 0;
    __syncthreads();

    int rbeg = b * CAPP;
    int rend = gcur[b];                 // multiple of 4, region int4-aligned
    for (int e = rbeg + tid * 4; e + 4 <= rend; e += 4096) {
        int4 p4 = *(const int4*)(packed + e);
        if (p4.x != -1) atomicAdd(&cnt[(p4.x >> 20) & (NPB - 1)], 1);
        if (p4.y != -1) atomicAdd(&cnt[(p4.y >> 20) & (NPB - 1)], 1);
        if (p4.z != -1) atomicAdd(&cnt[(p4.z >> 20) & (NPB - 1)], 1);
        if (p4.w != -1) atomicAdd(&cnt[(p4.w >> 20) & (NPB - 1)], 1);
    }
    __syncthreads();

    if (tid < NPB) {
        int node = (b << BSH2) + tid;
        if (node < N) {
            float df = (float)cnt[tid];
            df = df < 1.0f ? 1.0f : df;
            float r = rsqrtf(df);
            norm[node] = r;
            norm2[node] = r * r;
        }
    }
}

// ---------------- gather: edge-centric, LDS fp32 accumulation ----------------
// One block per 256-node dst bucket; 64 KB LDS accumulator (2 blocks/CU, 32 waves).
// Each 8-lane group handles one packed edge per iteration: lane sub loads 16 B
// (8 halves = features sub*8..sub*8+7) of the src row and atomically adds into
// the dst node's LDS row. Column XOR-swizzle (col = f ^ (l&31)) breaks the
// structured 16-way bank conflict into data-random ~2-4-way.
template <bool OUTHALF>
__global__ __launch_bounds__(1024) void gather_acc(const __half* __restrict__ x,
                                                   const int* __restrict__ packed,
                                                   const int* __restrict__ gcur,
                                                   const float* __restrict__ post,
                                                   void* __restrict__ outv, int N) {
    __shared__ float acc[NPB * D];     // 64 KB
    int b = blockIdx.x;
    int tid = threadIdx.x;

    float4* accv = (float4*)acc;
    #pragma unroll
    for (int i = 0; i < (NPB * D / 4) / 1024; i++)
        accv[tid + i * 1024] = make_float4(0.f, 0.f, 0.f, 0.f);
    __syncthreads();

    int rbeg = b * CAPP;
    int rend = gcur[b];
    int g   = (tid >> 3) & 7;          // edge slot within wave
    int sub = tid & 7;                 // 16 B slice within row
    int wid = tid >> 6;                // wave id 0..15
    const uint4* x16 = (const uint4*)x;

    for (int base = rbeg + wid * 8; base < rend; base += 128) {
        int entry = base + g;
        int pk = (entry < rend) ? packed[entry] : -1;
        if (pk != -1) {
            int s = pk & 0xFFFFF;
            int l = (pk >> 20) & (NPB - 1);
            uint4 u = x16[s * 8 + sub];
            float fv[8];
            float2 t;
            t = __half22float2(*(const __half2*)&u.x); fv[0] = t.x; fv[1] = t.y;
            t = __half22float2(*(const __half2*)&u.y); fv[2] = t.x; fv[3] = t.y;
            t = __half22float2(*(const __half2*)&u.z); fv[4] = t.x; fv[5] = t.y;
            t = __half22float2(*(const __half2*)&u.w); fv[6] = t.x; fv[7] = t.y;
            int e = l & 31;
            int rowb = l * D;
            int fbase = sub * 8;
            #pragma unroll
            for (int k = 0; k < 8; k++)
                atomicAdd(&acc[rowb + ((fbase + k) ^ e)], fv[k]);
        }
    }
    __syncthreads();

    // epilogue: 1024 threads = 256 nodes x 4 parts of 16 features
    int l = tid >> 2;
    int part = tid & 3;
    int gnode = (b << BSH2) + l;
    if (gnode < N) {
        float sc = post[gnode];
        int e = l & 31;
        int rowb = l * D;
        float v[16];
        #pragma unroll
        for (int i = 0; i < 16; i++)
            v[i] = acc[rowb + ((part * 16 + i) ^ e)] * sc;
        if (OUTHALF) {
            __half2 h[8];
            #pragma unroll
            for (int i = 0; i < 8; i++) h[i] = __floats2half2_rn(v[2 * i], v[2 * i + 1]);
            uint4 u0, u1;
            u0.x = *(unsigned int*)&h[0];
            u0.y = *(unsigned int*)&h[1];
            u0.z = *(unsigned int*)&h[2];
            u0.w = *(unsigned int*)&h[3];
            u1.x = *(unsigned int*)&h[4];
            u1.y = *(unsigned int*)&h[5];
            u1.z = *(unsigned int*)&h[6];
            u1.w = *(unsigned int*)&h[7];
            ((uint4*)outv)[(long)gnode * 8 + part * 2]     = u0;
            ((uint4*)outv)[(long)gnode * 8 + part * 2 + 1] = u1;
        } else {
            ((float4*)outv)[(long)gnode * 16 + part * 4 + 0] = make_float4(v[0], v[1], v[2], v[3]);
            ((float4*)outv)[(long)gnode * 16 + part * 4 + 1] = make_float4(v[4], v[5], v[6], v[7]);
            ((float4*)outv)[(long)gnode * 16 + part * 4 + 2] = make_float4(v[8], v[9], v[10], v[11]);
            ((float4*)outv)[(long)gnode * 16 + part * 4 + 3] = make_float4(v[12], v[13], v[14], v[15]);
        }
    }
}

// ---------------- fallback (atomic push, round-1, pure fp32) ----------------

__global__ void deg_kernel_f(const int* __restrict__ dst, float* __restrict__ deg, int E) {
    int e = blockIdx.x * blockDim.x + threadIdx.x;
    if (e < E) unsafeAtomicAdd(&deg[dst[e]], 1.0f);
}

__global__ void norm_kernel_f(float* __restrict__ deg_norm, float* __restrict__ norm2, int N) {
    int i = blockIdx.x * blockDim.x + threadIdx.x;
    if (i < N) {
        float d = deg_norm[i];
        d = d < 1.0f ? 1.0f : d;
        float r = rsqrtf(d);
        deg_norm[i] = r;
        norm2[i] = r * r;
    }
}

__global__ void scatter_kernel(const float* __restrict__ x,
                               const float* __restrict__ scale,
                               const int* __restrict__ src,
                               const int* __restrict__ dst,
                               float* __restrict__ out, int E) {
    long idx = (long)blockIdx.x * blockDim.x + threadIdx.x;
    int e = (int)(idx >> 6);
    int lane = (int)(idx & 63);
    if (e < E) {
        int s = src[e];
        int d0 = dst[e];
        float v = x[(long)s * D + lane] * scale[s];
        unsafeAtomicAdd(&out[(long)d0 * D + lane], v);
    }
}

__global__ void scale_kernel(float* __restrict__ out, const float* __restrict__ norm, long n) {
    long i = (long)blockIdx.x * blockDim.x + threadIdx.x;
    if (i < n) out[i] *= norm[i >> 6];
}

// ---------------- launch ----------------

extern "C" void kernel_launch(void* const* d_in, const int* in_sizes, int n_in,
                              void* d_out, int out_size, void* d_ws, size_t ws_size,
                              hipStream_t stream) {
    const float* feat = (const float*)d_in[0];
    const int*   src  = (const int*)d_in[1];
    const int*   dst  = (const int*)d_in[2];
    float* out = (float*)d_out;

    const int N = in_sizes[0] / D;   // 100000
    const int E = in_sizes[1];       // 1200000
    const long ND = (long)N * D;
    const int NB2 = (N + NPB - 1) >> BSH2;   // 256-node buckets

    // ws layout (4B elems):
    //   gcur[NB2_MAX] | norm[N] | norm2[N] | feat16[ND/2] | buf1h[ND/2] | packed[NB2*CAPP]
    //   (packed must survive both gather hops -- no aliasing)
    long o_gcur  = 0;
    long o_norm  = o_gcur + NB2_MAX;
    long o_norm2 = o_norm + N;
    long o_f16   = (o_norm2 + N + 3) & ~3L;
    long o_b1    = o_f16 + ND / 2;
    long o_pk    = o_b1 + ND / 2;
    size_t need = (size_t)(o_pk + (long)NB2 * CAPP) * 4;

    if (ws_size >= need && N <= (1 << 20) && NB2 <= NB2_MAX) {
        int*   bi = (int*)d_ws;
        float* bf = (float*)d_ws;
        int* gcur    = bi + o_gcur;
        float* norm  = bf + o_norm;
        float* norm2 = bf + o_norm2;
        __half* feat16 = (__half*)(bi + o_f16);   // [N][64] half, pre-scaled by norm
        __half* buf1h  = (__half*)(bi + o_b1);    // [N][64] half, hop-1 result
        int* packed  = bi + o_pk;

        int pblocks = (E + PCHUNK - 1) / PCHUNK;

        init_cursors<<<(NB2 + 255) / 256, 256, 0, stream>>>(gcur, NB2);
        partition_direct<<<pblocks, 1024, 0, stream>>>(src, dst, gcur, packed, E, NB2);
        bucket_norm<<<NB2, 1024, 0, stream>>>(packed, gcur, norm, norm2, N);
        long n4 = ND / 4;
        feat_to_half<<<(int)((n4 + 255) / 256), 256, 0, stream>>>(
            (const float4*)feat, norm, (uint2*)feat16, n4);

        // hop 1: buf1h = half( norm2 ⊙ S(feat16) )
        gather_acc<true><<<NB2, 1024, 0, stream>>>(feat16, packed, gcur, norm2, buf1h, N);
        // hop 2: out = norm ⊙ S(buf1h)   (fp32)
        gather_acc<false><<<NB2, 1024, 0, stream>>>(buf1h, packed, gcur, norm, out, N);
    } else {
        // fallback: atomic push mode (fp32, needs only 2N+ND floats)
        float* norm  = (float*)d_ws;
        float* norm2 = norm + N;
        float* buf1  = norm2 + N;

        long nz = 2L * N + ND;
        zero_f32<<<(int)((nz + 255) / 256), 256, 0, stream>>>((float*)d_ws, nz);
        zero_f32<<<(int)((ND + 255) / 256), 256, 0, stream>>>(out, ND);
        deg_kernel_f<<<(E + 255) / 256, 256, 0, stream>>>(dst, norm, E);
        norm_kernel_f<<<(N + 255) / 256, 256, 0, stream>>>(norm, norm2, N);
        long work = (long)E * D;
        int blocks = (int)((work + 255) / 256);
        scatter_kernel<<<blocks, 256, 0, stream>>>(feat, norm, src, dst, buf1, E);
        scatter_kernel<<<blocks, 256, 0, stream>>>(buf1, norm2, src, dst, out, E);
        scale_kernel<<<(int)((ND + 255) / 256), 256, 0, stream>>>(out, norm, ND);
    }
}

// Round 3
// 198.013 us; speedup vs baseline: 5.7164x; 5.7164x over previous
//
#include <hip/hip_runtime.h>
#include <hip/hip_fp16.h>

#define D 64
#define BSH2 8                   // 256 nodes per coarse bucket
#define NPB 256                  // nodes per bucket
#define NB2_MAX 512              // max buckets (N <= 131072)
#define PCHUNK 4096              // edges per partition block
#define CAPP 6144                // packed region capacity per bucket (incl. pad, x16)
#define CAP2 4096                // csr region capacity per bucket (real edges)

// ---------------- utility ----------------

__global__ void zero_f32(float* __restrict__ p, long n) {
    long i = (long)blockIdx.x * blockDim.x + threadIdx.x;
    long stride = (long)gridDim.x * blockDim.x;
    for (; i < n; i += stride) p[i] = 0.0f;
}

__global__ void init_cursors(int* __restrict__ gcur, int NB2) {
    int i = blockIdx.x * blockDim.x + threadIdx.x;
    if (i < NB2) gcur[i << 4] = i * CAPP;
}

// Quarter-major fp16 table: out layout [4][N][16] halves.
// Thread i handles input float4 i: node = i>>4, q = (i>>2)&3, j = i&3.
// Quarter table = 3.2 MB for N=100K -> per-XCD-L2 resident during quarter passes.
__global__ __launch_bounds__(256) void feat_to_half_q(const float4* __restrict__ in,
                                                      const float* __restrict__ norm,
                                                      uint2* __restrict__ out, int N) {
    long i = (long)blockIdx.x * blockDim.x + threadIdx.x;
    long n4 = (long)N * 16;
    if (i < n4) {
        float4 v = in[i];
        int node = (int)(i >> 4);
        int t = (int)(i & 15);
        int q = t >> 2, j = t & 3;
        float r = norm[node];
        __half2 a = __floats2half2_rn(v.x * r, v.y * r);
        __half2 b = __floats2half2_rn(v.z * r, v.w * r);
        uint2 u;
        u.x = *(unsigned int*)&a;
        u.y = *(unsigned int*)&b;
        out[(long)q * N * 4 + node * 4 + j] = u;
    }
}

// ---------------- build: single-pass partition (1024 threads) ----------------
__global__ __launch_bounds__(1024) void partition_direct(const int* __restrict__ src,
                                                         const int* __restrict__ dst,
                                                         int* __restrict__ gcur,  // stride 16
                                                         int* __restrict__ packed,
                                                         int E, int NB2) {
    __shared__ int staged[PCHUNK];     // 16 KB sorted chunk
    __shared__ int lhist[NB2_MAX];
    __shared__ int lbase[NB2_MAX];
    __shared__ int lcur[NB2_MAX];
    __shared__ int gbase[NB2_MAX];
    int tid = threadIdx.x;
    int c0 = blockIdx.x * PCHUNK;
    int c1 = c0 + PCHUNK; if (c1 > E) c1 = E;

    if (tid < NB2_MAX) lhist[tid] = 0;
    __syncthreads();

    // 1: histogram
    for (int e = c0 + tid * 4; e + 4 <= c1; e += 4096) {
        int4 d4 = *(const int4*)(dst + e);
        atomicAdd(&lhist[d4.x >> BSH2], 1);
        atomicAdd(&lhist[d4.y >> BSH2], 1);
        atomicAdd(&lhist[d4.z >> BSH2], 1);
        atomicAdd(&lhist[d4.w >> BSH2], 1);
    }
    int tail = c0 + ((c1 - c0) & ~3);
    for (int e = tail + tid; e < c1; e += 1024)
        atomicAdd(&lhist[dst[e] >> BSH2], 1);
    __syncthreads();

    // 2: single-wave exclusive scan over 512 counters (2 barriers total)
    if (tid < 64) {
        const int CPL = NB2_MAX / 64;     // 8 counters per lane
        int tmp[CPL];
        int s = 0;
        int base = tid * CPL;
        #pragma unroll
        for (int j = 0; j < CPL; j++) { tmp[j] = s; s += lhist[base + j]; }
        int incl = s;
        #pragma unroll
        for (int o = 1; o < 64; o <<= 1) {
            int t = __shfl_up(incl, o, 64);
            if (tid >= o) incl += t;
        }
        int excl = incl - s;
        #pragma unroll
        for (int j = 0; j < CPL; j++) {
            lbase[base + j] = excl + tmp[j];
            lcur[base + j]  = excl + tmp[j];
        }
    }
    __syncthreads();

    // 3: place chunk into LDS sorted by bucket
    for (int e = c0 + tid * 4; e + 4 <= c1; e += 4096) {
        int4 d4 = *(const int4*)(dst + e);
        int4 s4 = *(const int4*)(src + e);
        int k, pos;
        k = d4.x >> BSH2; pos = atomicAdd(&lcur[k], 1);
        staged[pos] = s4.x | ((d4.x & (NPB - 1)) << 20);
        k = d4.y >> BSH2; pos = atomicAdd(&lcur[k], 1);
        staged[pos] = s4.y | ((d4.y & (NPB - 1)) << 20);
        k = d4.z >> BSH2; pos = atomicAdd(&lcur[k], 1);
        staged[pos] = s4.z | ((d4.z & (NPB - 1)) << 20);
        k = d4.w >> BSH2; pos = atomicAdd(&lcur[k], 1);
        staged[pos] = s4.w | ((d4.w & (NPB - 1)) << 20);
    }
    for (int e = tail + tid; e < c1; e += 1024) {
        int d = dst[e];
        int k = d >> BSH2;
        int pos = atomicAdd(&lcur[k], 1);
        staged[pos] = src[e] | ((d & (NPB - 1)) << 20);
    }
    __syncthreads();

    // 4: parallel reservations
    if (tid < NB2_MAX && tid < NB2) {
        int c = lhist[tid];
        gbase[tid] = c ? atomicAdd(&gcur[tid << 4], (c + 15) & ~15) : 0;
    }
    __syncthreads();

    // 5: flush — 64 groups of 16 lanes stream full 64B lines
    int grp = tid >> 4, sub = tid & 15;
    for (int k = grp; k < NB2; k += 64) {
        int c = lhist[k];
        if (!c) continue;
        int c16 = (c + 15) & ~15;
        int g = gbase[k], base = lbase[k];
        for (int i = sub; i < c16; i += 16)
            packed[g + i] = (i < c) ? staged[base + i] : -1;
    }
}

// ---------------- build: per-bucket CSR + norms (1024 threads) ----------------
__global__ __launch_bounds__(1024) void bucket_csr(const int* __restrict__ packed,
                                                   const int* __restrict__ gcur,
                                                   int2* __restrict__ rbc,
                                                   float* __restrict__ norm,
                                                   float* __restrict__ norm2,
                                                   int* __restrict__ csr,
                                                   int N, int NB2) {
    __shared__ int cnt[NPB];
    __shared__ int loc[NPB];
    int b = blockIdx.x;
    int tid = threadIdx.x;
    if (tid < NPB) cnt[tid] = 0;
    __syncthreads();

    int rbeg = b * CAPP;
    int rend = gcur[b << 4];
    // sweep 1: per-node counts (int4)
    for (int e = rbeg + tid * 4; e + 4 <= rend; e += 4096) {
        int4 p4 = *(const int4*)(packed + e);
        if (p4.x != -1) atomicAdd(&cnt[(p4.x >> 20) & (NPB - 1)], 1);
        if (p4.y != -1) atomicAdd(&cnt[(p4.y >> 20) & (NPB - 1)], 1);
        if (p4.z != -1) atomicAdd(&cnt[(p4.z >> 20) & (NPB - 1)], 1);
        if (p4.w != -1) atomicAdd(&cnt[(p4.w >> 20) & (NPB - 1)], 1);
    }
    __syncthreads();
    // single-wave exclusive scan over 256 counters -> loc
    if (tid < 64) {
        int tmp[4];
        int s = 0;
        int base = tid * 4;
        #pragma unroll
        for (int j = 0; j < 4; j++) { tmp[j] = s; s += cnt[base + j]; }
        int incl = s;
        #pragma unroll
        for (int o = 1; o < 64; o <<= 1) {
            int t = __shfl_up(incl, o, 64);
            if (tid >= o) incl += t;
        }
        int excl = incl - s;
        #pragma unroll
        for (int j = 0; j < 4; j++) loc[base + j] = excl + tmp[j];
    }
    __syncthreads();

    // per-node outputs
    int cbase = b * CAP2;
    if (tid < NPB) {
        int node = (b << BSH2) + tid;
        if (node < N) {
            int v = cnt[tid];
            int ep = loc[tid];
            rbc[node] = make_int2(cbase + ep, v);
            float df = (float)v; df = df < 1.0f ? 1.0f : df;
            float r = rsqrtf(df);
            norm[node] = r;
            norm2[node] = r * r;
        }
    }
    __syncthreads();
    // sweep 2: place compacted csr (loc doubles as placement cursor)
    for (int e = rbeg + tid * 4; e + 4 <= rend; e += 4096) {
        int4 p4 = *(const int4*)(packed + e);
        int l, pos;
        if (p4.x != -1) { l = (p4.x >> 20) & (NPB - 1); pos = atomicAdd(&loc[l], 1); csr[cbase + pos] = p4.x & 0xFFFFF; }
        if (p4.y != -1) { l = (p4.y >> 20) & (NPB - 1); pos = atomicAdd(&loc[l], 1); csr[cbase + pos] = p4.y & 0xFFFFF; }
        if (p4.z != -1) { l = (p4.z >> 20) & (NPB - 1); pos = atomicAdd(&loc[l], 1); csr[cbase + pos] = p4.z & 0xFFFFF; }
        if (p4.w != -1) { l = (p4.w >> 20) & (NPB - 1); pos = atomicAdd(&loc[l], 1); csr[cbase + pos] = p4.w & 0xFFFFF; }
    }
}

// ---------------- gather: quarter-split, one node per 2-lane group ----------------
// Table xq is quarter-major [4][N][16] halves; quarter q = blockIdx.x / nbq so
// dispatch order keeps quarters temporally separated (validated in R1: L2-resident).
// 256 threads = 128 groups of 2 lanes; group owns node w = b*128 + (tid>>1).
// Per wave instruction: 32 independent 32 B row requests; masked 4-wide unroll
// gives ~128 requests in flight per wave -> covers L2 latency (R1 had ~2).
// No LDS, no barriers, no shuffles: each group's accumulator lives in registers.
template <bool OUTHALF>
__global__ __launch_bounds__(256) void gather_pull(const __half* __restrict__ xq,
                                                   const int2* __restrict__ rbc,
                                                   const int* __restrict__ csr,
                                                   const float* __restrict__ post,
                                                   void* __restrict__ outv,
                                                   int N, int nbq) {
    int q = blockIdx.x / nbq;
    int b = blockIdx.x - q * nbq;
    int grp = threadIdx.x >> 1;
    int sub = threadIdx.x & 1;
    int w = b * 128 + grp;
    if (w >= N) return;
    int2 bc = rbc[w];
    int beg = bc.x, end = bc.x + bc.y;
    const uint4* x16 = ((const uint4*)xq) + (long)q * N * 2;   // quarter row = 2 uint4

    float a0 = 0.f, a1 = 0.f, a2 = 0.f, a3 = 0.f;
    float a4 = 0.f, a5 = 0.f, a6 = 0.f, a7 = 0.f;

    for (int e = beg; e < end; e += 4) {
        // clamp indices into range; mask contributions of clamped slots.
        int e1 = e + 1, e2 = e + 2, e3 = e + 3;
        float m1 = (e1 < end) ? 1.f : 0.f; if (e1 >= end) e1 = end - 1;
        float m2 = (e2 < end) ? 1.f : 0.f; if (e2 >= end) e2 = end - 1;
        float m3 = (e3 < end) ? 1.f : 0.f; if (e3 >= end) e3 = end - 1;
        int s0 = csr[e];
        int s1 = csr[e1];
        int s2 = csr[e2];
        int s3 = csr[e3];
        uint4 u0 = x16[s0 * 2 + sub];
        uint4 u1 = x16[s1 * 2 + sub];
        uint4 u2 = x16[s2 * 2 + sub];
        uint4 u3 = x16[s3 * 2 + sub];
        float2 f;
        f = __half22float2(*(const __half2*)&u0.x); a0 += f.x; a1 += f.y;
        f = __half22float2(*(const __half2*)&u0.y); a2 += f.x; a3 += f.y;
        f = __half22float2(*(const __half2*)&u0.z); a4 += f.x; a5 += f.y;
        f = __half22float2(*(const __half2*)&u0.w); a6 += f.x; a7 += f.y;
        f = __half22float2(*(const __half2*)&u1.x); a0 += f.x * m1; a1 += f.y * m1;
        f = __half22float2(*(const __half2*)&u1.y); a2 += f.x * m1; a3 += f.y * m1;
        f = __half22float2(*(const __half2*)&u1.z); a4 += f.x * m1; a5 += f.y * m1;
        f = __half22float2(*(const __half2*)&u1.w); a6 += f.x * m1; a7 += f.y * m1;
        f = __half22float2(*(const __half2*)&u2.x); a0 += f.x * m2; a1 += f.y * m2;
        f = __half22float2(*(const __half2*)&u2.y); a2 += f.x * m2; a3 += f.y * m2;
        f = __half22float2(*(const __half2*)&u2.z); a4 += f.x * m2; a5 += f.y * m2;
        f = __half22float2(*(const __half2*)&u2.w); a6 += f.x * m2; a7 += f.y * m2;
        f = __half22float2(*(const __half2*)&u3.x); a0 += f.x * m3; a1 += f.y * m3;
        f = __half22float2(*(const __half2*)&u3.y); a2 += f.x * m3; a3 += f.y * m3;
        f = __half22float2(*(const __half2*)&u3.z); a4 += f.x * m3; a5 += f.y * m3;
        f = __half22float2(*(const __half2*)&u3.w); a6 += f.x * m3; a7 += f.y * m3;
    }

    float pn = post[w];
    a0 *= pn; a1 *= pn; a2 *= pn; a3 *= pn;
    a4 *= pn; a5 *= pn; a6 *= pn; a7 *= pn;
    if (OUTHALF) {
        __half2 h0 = __floats2half2_rn(a0, a1);
        __half2 h1 = __floats2half2_rn(a2, a3);
        __half2 h2 = __floats2half2_rn(a4, a5);
        __half2 h3 = __floats2half2_rn(a6, a7);
        uint4 u;
        u.x = *(unsigned int*)&h0;
        u.y = *(unsigned int*)&h1;
        u.z = *(unsigned int*)&h2;
        u.w = *(unsigned int*)&h3;
        ((uint4*)outv)[(long)q * N * 2 + (long)w * 2 + sub] = u;
    } else {
        float4 r0; r0.x = a0; r0.y = a1; r0.z = a2; r0.w = a3;
        float4 r1; r1.x = a4; r1.y = a5; r1.z = a6; r1.w = a7;
        ((float4*)outv)[(long)w * 16 + q * 4 + sub * 2]     = r0;
        ((float4*)outv)[(long)w * 16 + q * 4 + sub * 2 + 1] = r1;
    }
}

// ---------------- fallback (atomic push, round-1, pure fp32) ----------------

__global__ void deg_kernel_f(const int* __restrict__ dst, float* __restrict__ deg, int E) {
    int e = blockIdx.x * blockDim.x + threadIdx.x;
    if (e < E) unsafeAtomicAdd(&deg[dst[e]], 1.0f);
}

__global__ void norm_kernel_f(float* __restrict__ deg_norm, float* __restrict__ norm2, int N) {
    int i = blockIdx.x * blockDim.x + threadIdx.x;
    if (i < N) {
        float d = deg_norm[i];
        d = d < 1.0f ? 1.0f : d;
        float r = rsqrtf(d);
        deg_norm[i] = r;
        norm2[i] = r * r;
    }
}

__global__ void scatter_kernel(const float* __restrict__ x,
                               const float* __restrict__ scale,
                               const int* __restrict__ src,
                               const int* __restrict__ dst,
                               float* __restrict__ out, int E) {
    long idx = (long)blockIdx.x * blockDim.x + threadIdx.x;
    int e = (int)(idx >> 6);
    int lane = (int)(idx & 63);
    if (e < E) {
        int s = src[e];
        int d0 = dst[e];
        float v = x[(long)s * D + lane] * scale[s];
        unsafeAtomicAdd(&out[(long)d0 * D + lane], v);
    }
}

__global__ void scale_kernel(float* __restrict__ out, const float* __restrict__ norm, long n) {
    long i = (long)blockIdx.x * blockDim.x + threadIdx.x;
    if (i < n) out[i] *= norm[i >> 6];
}

// ---------------- launch ----------------

extern "C" void kernel_launch(void* const* d_in, const int* in_sizes, int n_in,
                              void* d_out, int out_size, void* d_ws, size_t ws_size,
                              hipStream_t stream) {
    const float* feat = (const float*)d_in[0];
    const int*   src  = (const int*)d_in[1];
    const int*   dst  = (const int*)d_in[2];
    float* out = (float*)d_out;

    const int N = in_sizes[0] / D;   // 100000
    const int E = in_sizes[1];       // 1200000
    const long ND = (long)N * D;
    const int NB2 = (N + NPB - 1) >> BSH2;   // 256-node buckets

    // ws layout (4B elems):
    //   gcur[NB2_MAX*16] | rbc[2N] (int2) | norm[N] | norm2[N] |
    //   csr[NB2*CAP2] | feat16[ND/2] | buf1h[max(ND/2, NB2*CAPP)]
    //   (packed regions alias buf1h -- dead before gather1 writes buf1h)
    long o_gcur = 0;
    long o_rbc  = o_gcur + NB2_MAX * 16;      // even -> int2 aligned
    long o_norm = o_rbc + 2L * N;
    long o_norm2 = o_norm + N;
    long o_csr  = (o_norm2 + N + 3) & ~3L;
    long o_f16  = (o_csr + (long)NB2 * CAP2 + 3) & ~3L;
    long o_buf1 = (o_f16 + ND / 2 + 3) & ~3L;
    long pk_len = (long)NB2 * CAPP;
    long buf1_len = (ND / 2 > pk_len) ? ND / 2 : pk_len;
    size_t need = (size_t)(o_buf1 + buf1_len) * 4;

    if (ws_size >= need && N <= (1 << 20) && NB2 <= NB2_MAX) {
        int*   bi = (int*)d_ws;
        float* bf = (float*)d_ws;
        int* gcur    = bi + o_gcur;
        int2* rbc    = (int2*)(bi + o_rbc);
        float* norm  = bf + o_norm;
        float* norm2 = bf + o_norm2;
        int* csr     = bi + o_csr;
        __half* feat16 = (__half*)(bi + o_f16);   // quarter-major [4][N][16]
        __half* buf1h  = (__half*)(bi + o_buf1);  // quarter-major [4][N][16]
        int* packed  = bi + o_buf1;

        int pblocks = (E + PCHUNK - 1) / PCHUNK;

        init_cursors<<<(NB2 + 255) / 256, 256, 0, stream>>>(gcur, NB2);
        partition_direct<<<pblocks, 1024, 0, stream>>>(src, dst, gcur, packed, E, NB2);
        bucket_csr<<<NB2, 1024, 0, stream>>>(packed, gcur, rbc, norm, norm2, csr, N, NB2);
        // feat16[q][node][16] = half(norm[node] * feat[node][q*16..])
        long n4 = ND / 4;
        feat_to_half_q<<<(int)((n4 + 255) / 256), 256, 0, stream>>>(
            (const float4*)feat, norm, (uint2*)feat16, N);

        int nbq = (N + 127) / 128;   // blocks per quarter-pass (128 nodes/block)
        // hop 1: buf1h[q] = half( norm2 ⊙ S(feat16[q]) ), 4 quarter passes in one launch
        gather_pull<true><<<nbq * 4, 256, 0, stream>>>(feat16, rbc, csr, norm2, buf1h, N, nbq);
        // hop 2: out = norm ⊙ S(buf1h)   (fp32 row-major)
        gather_pull<false><<<nbq * 4, 256, 0, stream>>>(buf1h, rbc, csr, norm, out, N, nbq);
    } else {
        // fallback: atomic push mode (fp32, needs only 2N+ND floats)
        float* norm  = (float*)d_ws;
        float* norm2 = norm + N;
        float* buf1  = norm2 + N;

        long nz = 2L * N + ND;
        zero_f32<<<(int)((nz + 255) / 256), 256, 0, stream>>>((float*)d_ws, nz);
        zero_f32<<<(int)((ND + 255) / 256), 256, 0, stream>>>(out, ND);
        deg_kernel_f<<<(E + 255) / 256, 256, 0, stream>>>(dst, norm, E);
        norm_kernel_f<<<(N + 255) / 256, 256, 0, stream>>>(norm, norm2, N);
        long work = (long)E * D;
        int blocks = (int)((work + 255) / 256);
        scatter_kernel<<<blocks, 256, 0, stream>>>(feat, norm, src, dst, buf1, E);
        scatter_kernel<<<blocks, 256, 0, stream>>>(buf1, norm2, src, dst, out, E);
        scale_kernel<<<(int)((ND + 255) / 256), 256, 0, stream>>>(out, norm, ND);
    }
}